// Round 3
// baseline (245.795 us; speedup 1.0000x reference)
//
#include <hip/hip_runtime.h>
#include <hip/hip_bf16.h>
#include <stdint.h>

#define DEV_INLINE __device__ __forceinline__

typedef unsigned short u16;
typedef __attribute__((ext_vector_type(8))) __bf16 bf16x8;
typedef __attribute__((ext_vector_type(4))) float f32x4;

constexpr int Bc = 2, Sc = 2048, Dc = 1024, Hc = 16, HDc = 64;
constexpr int Kdim = 1024;
constexpr size_t SEG4M = 4194304;   // 4M elems
constexpr size_t SEG1M = 1048576;   // 1M elems

DEV_INLINE u16 f32_to_bf16(float f) {
    unsigned int u = __builtin_bit_cast(unsigned int, f);
    unsigned int r = (u + 0x7fffu + ((u >> 16) & 1u)) >> 16;
    return (u16)r;
}

DEV_INLINE f32x4 mfma16(bf16x8 a, bf16x8 b, f32x4 c) {
    return __builtin_amdgcn_mfma_f32_16x16x32_bf16(a, b, c, 0, 0, 0);
}

// async global->LDS, 16B per lane; lds dest must be wave-uniform base.
DEV_INLINE void gload_lds16(const u16* g, u16* lds) {
    __builtin_amdgcn_global_load_lds(
        (const __attribute__((address_space(1))) void*)g,
        (__attribute__((address_space(3))) void*)lds,
        16, 0, 0);
}

// ---------------- fp32 -> bf16, all 7 tensors in one launch ----------------
__global__ __launch_bounds__(256) void cvt_all_kernel(
        const float* __restrict__ q, const float* __restrict__ k,
        const float* __restrict__ v, const float* __restrict__ wq,
        const float* __restrict__ wk, const float* __restrict__ wv,
        const float* __restrict__ wo, u16* __restrict__ dst) {
    int b = blockIdx.x;
    const float* src; size_t doff; int lb;
    if (b < 2048)      { src = q;  lb = b;        doff = 0; }
    else if (b < 4096) { src = k;  lb = b - 2048; doff = SEG4M; }
    else if (b < 6144) { src = v;  lb = b - 4096; doff = 2 * SEG4M; }
    else if (b < 6656) { src = wq; lb = b - 6144; doff = 3 * SEG4M; }
    else if (b < 7168) { src = wk; lb = b - 6656; doff = 3 * SEG4M + SEG1M; }
    else if (b < 7680) { src = wv; lb = b - 7168; doff = 3 * SEG4M + 2 * SEG1M; }
    else               { src = wo; lb = b - 7680; doff = 3 * SEG4M + 3 * SEG1M; }
    size_t i = ((size_t)lb * 256 + threadIdx.x) * 8;
    float4 a = *reinterpret_cast<const float4*>(src + i);
    float4 c = *reinterpret_cast<const float4*>(src + i + 4);
    union { u16 u[8]; uint4 v4; } o;
    o.u[0] = f32_to_bf16(a.x); o.u[1] = f32_to_bf16(a.y);
    o.u[2] = f32_to_bf16(a.z); o.u[3] = f32_to_bf16(a.w);
    o.u[4] = f32_to_bf16(c.x); o.u[5] = f32_to_bf16(c.y);
    o.u[6] = f32_to_bf16(c.z); o.u[7] = f32_to_bf16(c.w);
    *reinterpret_cast<uint4*>(dst + doff + i) = o.v4;
}

// ---------------- fused QKV projection: 128x128 tiles, global_load_lds -----
__global__ __launch_bounds__(256, 3) void gemm_qkv_kernel(
        const u16* __restrict__ Xb, const u16* __restrict__ Wb,
        u16* __restrict__ Ob) {
    __shared__ u16 Al[128 * 64];
    __shared__ u16 Bl[128 * 64];
    const int tid = threadIdx.x;
    const int l = tid & 63, w = tid >> 6;
    const int wm = w >> 1, wn = w & 1;
    const int l15 = l & 15, lg = l >> 4;
    const int lr = l >> 3, lc = (l & 7) * 8;

    int bid = blockIdx.x;                       // 768 blocks
    int wid = (bid & 7) * 96 + (bid >> 3);      // XCD-contiguous
    int mt = wid / 24, nt = wid % 24;
    int seg = nt >> 3, ntl = nt & 7;

    const u16* A = Xb + (size_t)seg * SEG4M + (size_t)mt * 128 * Kdim;
    const u16* W = Wb + (size_t)seg * SEG1M + (size_t)ntl * 128 * Kdim;

    f32x4 acc[4][4] = {};

    for (int kt = 0; kt < 16; ++kt) {
        const int kb = kt * 64;
#pragma unroll
        for (int i = 0; i < 4; ++i) {
            int j = w * 4 + i;
            gload_lds16(A + (size_t)(j * 8 + lr) * Kdim + kb + lc, &Al[j * 512]);
            gload_lds16(W + (size_t)(j * 8 + lr) * Kdim + kb + lc, &Bl[j * 512]);
        }
        asm volatile("s_waitcnt vmcnt(0)" ::: "memory");
        __syncthreads();
#pragma unroll
        for (int kk = 0; kk < 2; ++kk) {
            bf16x8 af[4], bfr[4];
#pragma unroll
            for (int mi = 0; mi < 4; ++mi)
                af[mi] = *reinterpret_cast<const bf16x8*>(&Al[(wm * 64 + mi * 16 + l15) * 64 + kk * 32 + lg * 8]);
#pragma unroll
            for (int ni = 0; ni < 4; ++ni)
                bfr[ni] = *reinterpret_cast<const bf16x8*>(&Bl[(wn * 64 + ni * 16 + l15) * 64 + kk * 32 + lg * 8]);
#pragma unroll
            for (int mi = 0; mi < 4; ++mi)
#pragma unroll
                for (int ni = 0; ni < 4; ++ni)
                    acc[mi][ni] = mfma16(af[mi], bfr[ni], acc[mi][ni]);
        }
        __syncthreads();
    }

    const float scale = (seg == 0) ? 0.125f : 1.0f;
    u16* out = Ob + (size_t)seg * SEG4M;
    const int row0 = mt * 128 + wm * 64;
    const int col0 = ntl * 128 + wn * 64;
#pragma unroll
    for (int mi = 0; mi < 4; ++mi)
#pragma unroll
        for (int r = 0; r < 4; ++r) {
            int m = row0 + mi * 16 + lg * 4 + r;
            int b = m >> 11, s = m & 2047;
#pragma unroll
            for (int ni = 0; ni < 4; ++ni) {
                int n = col0 + ni * 16 + l15;
                int h = n >> 6, d = n & 63;
                out[(((size_t)b * Hc + h) * Sc + s) * HDc + d] =
                    f32_to_bf16(acc[mi][ni][r] * scale);
            }
        }
}

// ---------------- output projection: 128x64 tiles -> fp32 ------------------
__global__ __launch_bounds__(256, 3) void gemm_out_kernel(
        const u16* __restrict__ A0, const u16* __restrict__ W0,
        float* __restrict__ outf) {
    __shared__ u16 Al[128 * 64];
    __shared__ u16 Bl[64 * 64];
    const int tid = threadIdx.x;
    const int l = tid & 63, w = tid >> 6;
    const int l15 = l & 15, lg = l >> 4;
    const int lr = l >> 3, lc = (l & 7) * 8;

    int bid = blockIdx.x;                      // 512 blocks
    int wid = (bid & 7) * 64 + (bid >> 3);
    int mt = wid >> 4, nt = wid & 15;

    const u16* A = A0 + (size_t)mt * 128 * Kdim;
    const u16* W = W0 + (size_t)nt * 64 * Kdim;

    f32x4 acc[2][4] = {};

    for (int kt = 0; kt < 16; ++kt) {
        const int kb = kt * 64;
#pragma unroll
        for (int i = 0; i < 4; ++i) {
            int j = w * 4 + i;
            gload_lds16(A + (size_t)(j * 8 + lr) * Kdim + kb + lc, &Al[j * 512]);
        }
#pragma unroll
        for (int i = 0; i < 2; ++i) {
            int j = w * 2 + i;
            gload_lds16(W + (size_t)(j * 8 + lr) * Kdim + kb + lc, &Bl[j * 512]);
        }
        asm volatile("s_waitcnt vmcnt(0)" ::: "memory");
        __syncthreads();
#pragma unroll
        for (int kk = 0; kk < 2; ++kk) {
            bf16x8 af[2], bfr[4];
#pragma unroll
            for (int mi = 0; mi < 2; ++mi)
                af[mi] = *reinterpret_cast<const bf16x8*>(&Al[(w * 32 + mi * 16 + l15) * 64 + kk * 32 + lg * 8]);
#pragma unroll
            for (int ni = 0; ni < 4; ++ni)
                bfr[ni] = *reinterpret_cast<const bf16x8*>(&Bl[(ni * 16 + l15) * 64 + kk * 32 + lg * 8]);
#pragma unroll
            for (int mi = 0; mi < 2; ++mi)
#pragma unroll
                for (int ni = 0; ni < 4; ++ni)
                    acc[mi][ni] = mfma16(af[mi], bfr[ni], acc[mi][ni]);
        }
        __syncthreads();
    }

#pragma unroll
    for (int mi = 0; mi < 2; ++mi)
#pragma unroll
        for (int r = 0; r < 4; ++r) {
            int m = mt * 128 + w * 32 + mi * 16 + lg * 4 + r;
#pragma unroll
            for (int ni = 0; ni < 4; ++ni) {
                int n = nt * 64 + ni * 16 + l15;
                outf[(size_t)m * 1024 + n] = acc[mi][ni][r];
            }
        }
}

// ---------------- Vh (BH,S,64) -> Vt (BH,64,S) ----------------------------
__global__ __launch_bounds__(256) void transpose_v_kernel(const u16* __restrict__ Vh,
                                                          u16* __restrict__ Vt) {
    __shared__ u16 tb[64][72];
    const int tid = threadIdx.x;
    const int st = blockIdx.x * 64;
    const int bh = blockIdx.y;
    const u16* src = Vh + ((size_t)bh * Sc + st) * 64;
#pragma unroll
    for (int i = 0; i < 2; ++i) {
        int f = i * 256 + tid, r = f >> 3, cc = (f & 7) * 8;
        *reinterpret_cast<uint4*>(&tb[r][cc]) =
            *reinterpret_cast<const uint4*>(src + r * 64 + cc);
    }
    __syncthreads();
    u16* dst = Vt + (size_t)bh * 64 * Sc + st;
#pragma unroll
    for (int i = 0; i < 2; ++i) {
        int f = i * 256 + tid, d = f >> 3, s0 = (f & 7) * 8;
        union { u16 u[8]; uint4 v; } o;
#pragma unroll
        for (int j = 0; j < 8; ++j) o.u[j] = tb[s0 + j][d];
        *reinterpret_cast<uint4*>(dst + (size_t)d * Sc + s0) = o.v;
    }
}

// ---------------- causal flash attention, barrier-free ---------------------
// Qh,Kh: (BH,S,64) bf16 (Q pre-scaled); Vt: (BH,64,S) bf16.
// Grid 512 = 16 qt x 32 bh (bh = bid&31 -> bh%8 pins each bh to one XCD;
// K+V per bh = 512KB -> L2-resident, so NO LDS staging, NO __syncthreads).
// Block: 8 waves x 16 q-rows = 128 rows; each wave runs its own causal
// trip count. Only P re-fragmentation uses per-wave LDS.
__global__ __launch_bounds__(512, 4) void flash_attn_kernel(
        const u16* __restrict__ Qh, const u16* __restrict__ Kh,
        const u16* __restrict__ Vt, u16* __restrict__ Ctx) {
    __shared__ u16 Psh[8][16][72];

    const int tid = threadIdx.x;
    const int l = tid & 63, w = tid >> 6;
    const int l15 = l & 15, lg = l >> 4;

    const int bid = blockIdx.x;
    const int bh = bid & 31;                 // XCD = bh%8 -> 4 bh per XCD
    const int qt = 15 - (bid >> 5);          // big q-tiles dispatched first
    const int b = bh >> 4, h = bh & 15;
    const int qr0 = qt * 128 + w * 16;       // this wave's 16 q-rows

    const u16* qb = Qh + ((size_t)bh * Sc + qr0) * 64;
    bf16x8 aq[2];
#pragma unroll
    for (int kk = 0; kk < 2; ++kk)
        aq[kk] = *reinterpret_cast<const bf16x8*>(qb + l15 * 64 + kk * 32 + lg * 8);

    f32x4 o[4] = {};
    float m_run[4], l_run[4];
#pragma unroll
    for (int r = 0; r < 4; ++r) { m_run[r] = -1e30f; l_run[r] = 0.f; }

    const u16* kb0 = Kh + (size_t)bh * Sc * 64;
    const u16* vb0 = Vt + (size_t)bh * 64 * Sc;
    const int kt_max = qr0 >> 6;             // inclusive diagonal tile
    const int rbase = (qr0 & 63) + lg * 4;   // row-in-tile base for masking

    for (int kt = 0; kt <= kt_max; ++kt) {
        const u16* kbase = kb0 + (size_t)kt * 64 * 64;
        const u16* vbase = vb0 + (size_t)kt * 64;

        // S = Q K^T, fragments straight from L1/L2
        bf16x8 kf[2][4];
#pragma unroll
        for (int kk = 0; kk < 2; ++kk)
#pragma unroll
            for (int nk = 0; nk < 4; ++nk)
                kf[kk][nk] = *reinterpret_cast<const bf16x8*>(
                    kbase + (size_t)(nk * 16 + l15) * 64 + kk * 32 + lg * 8);
        f32x4 sc[4] = {};
        __builtin_amdgcn_s_setprio(1);
#pragma unroll
        for (int kk = 0; kk < 2; ++kk)
#pragma unroll
            for (int nk = 0; nk < 4; ++nk)
                sc[nk] = mfma16(aq[kk], kf[kk][nk], sc[nk]);
        __builtin_amdgcn_s_setprio(0);

        // causal mask only on the diagonal tile
        if (kt == kt_max) {
#pragma unroll
            for (int r = 0; r < 4; ++r)
#pragma unroll
                for (int nk = 0; nk < 4; ++nk)
                    if (nk * 16 + l15 > rbase + r) sc[nk][r] = -1e30f;
        }

        // online softmax with defer-max (T13, THR=8)
#pragma unroll
        for (int r = 0; r < 4; ++r) {
            float pmax = fmaxf(fmaxf(sc[0][r], sc[1][r]), fmaxf(sc[2][r], sc[3][r]));
            pmax = fmaxf(pmax, __shfl_xor(pmax, 1));
            pmax = fmaxf(pmax, __shfl_xor(pmax, 2));
            pmax = fmaxf(pmax, __shfl_xor(pmax, 4));
            pmax = fmaxf(pmax, __shfl_xor(pmax, 8));
            if (pmax > m_run[r] + 8.f) {
                float alpha = __expf(m_run[r] - pmax);
                l_run[r] *= alpha;
#pragma unroll
                for (int nd = 0; nd < 4; ++nd) o[nd][r] *= alpha;
                m_run[r] = pmax;
            }
            float ssum = 0.f;
#pragma unroll
            for (int nk = 0; nk < 4; ++nk) {
                float p = __expf(sc[nk][r] - m_run[r]);
                sc[nk][r] = p;
                ssum += p;
            }
            ssum += __shfl_xor(ssum, 1);
            ssum += __shfl_xor(ssum, 2);
            ssum += __shfl_xor(ssum, 4);
            ssum += __shfl_xor(ssum, 8);
            l_run[r] += ssum;
        }

        // P -> per-wave LDS slice (re-fragment for PV A-operand)
#pragma unroll
        for (int r = 0; r < 4; ++r)
#pragma unroll
            for (int nk = 0; nk < 4; ++nk)
                Psh[w][lg * 4 + r][nk * 16 + l15] = f32_to_bf16(sc[nk][r]);
        asm volatile("s_waitcnt lgkmcnt(0)" ::: "memory");
        __builtin_amdgcn_sched_barrier(0);

        // O += P V  (V fragments straight from L2; Vt rows = d)
        bf16x8 vf[2][4];
#pragma unroll
        for (int kk = 0; kk < 2; ++kk)
#pragma unroll
            for (int nd = 0; nd < 4; ++nd)
                vf[kk][nd] = *reinterpret_cast<const bf16x8*>(
                    vbase + (size_t)(nd * 16 + l15) * Sc + kk * 32 + lg * 8);
        __builtin_amdgcn_s_setprio(1);
#pragma unroll
        for (int kk = 0; kk < 2; ++kk) {
            bf16x8 pa = *reinterpret_cast<const bf16x8*>(&Psh[w][l15][kk * 32 + lg * 8]);
#pragma unroll
            for (int nd = 0; nd < 4; ++nd)
                o[nd] = mfma16(pa, vf[kk][nd], o[nd]);
        }
        __builtin_amdgcn_s_setprio(0);
    }

    // epilogue: normalize, write Ctx (B,S,D) bf16
#pragma unroll
    for (int r = 0; r < 4; ++r) {
        int srow = qr0 + lg * 4 + r;
        float inv = 1.f / l_run[r];
        size_t base = ((size_t)b * Sc + srow) * Dc + h * 64;
#pragma unroll
        for (int nd = 0; nd < 4; ++nd)
            Ctx[base + nd * 16 + l15] = f32_to_bf16(o[nd][r] * inv);
    }
}

// ---------------------------------------------------------------------------
extern "C" void kernel_launch(void* const* d_in, const int* in_sizes, int n_in,
                              void* d_out, int out_size, void* d_ws, size_t ws_size,
                              hipStream_t stream) {
    const float* q  = (const float*)d_in[0];
    const float* k  = (const float*)d_in[1];
    const float* v  = (const float*)d_in[2];
    const float* Wq = (const float*)d_in[4];
    const float* Wk = (const float*)d_in[5];
    const float* Wv = (const float*)d_in[6];
    const float* Wo = (const float*)d_in[7];

    u16* ws = (u16*)d_ws;
    u16* Xq  = ws;                       // 3 x 4M input bf16 (contiguous)
    u16* Wqb = ws + 3 * SEG4M;           // 4 x 1M weights bf16 (contiguous)
    u16* Wob = Wqb + 3 * SEG1M;
    u16* Qh  = ws + 4 * SEG4M;           // 3 x 4M head-layout (contiguous)
    u16* Kh  = Qh + SEG4M;
    u16* Vh  = Kh + SEG4M;
    u16* Vtr = ws + SEG4M;               // alias Xk (dead after gemm_qkv)
    u16* Ctx = ws;                       // alias Xq (dead after gemm_qkv)

    // 1) all conversions, one launch
    cvt_all_kernel<<<8192, 256, 0, stream>>>(q, k, v, Wq, Wk, Wv, Wo, ws);

    // 2) fused QKV projection (scale 1/8 folded into Q)
    gemm_qkv_kernel<<<768, 256, 0, stream>>>(Xq, Wqb, Qh);

    // 3) V transpose for contiguous PV fragments
    transpose_v_kernel<<<dim3(32, 32), 256, 0, stream>>>(Vh, Vtr);

    // 4) causal flash attention (barrier-free)
    flash_attn_kernel<<<512, 512, 0, stream>>>(Qh, Kh, Vtr, Ctx);

    // 5) output projection -> fp32
    gemm_out_kernel<<<512, 256, 0, stream>>>(Ctx, Wob, (float*)d_out);
}

// Round 4
// 149.717 us; speedup vs baseline: 1.6417x; 1.6417x over previous
//
#include <hip/hip_runtime.h>
#include <hip/hip_bf16.h>
#include <stdint.h>

#define DEV_INLINE __device__ __forceinline__

typedef unsigned short u16;
typedef __attribute__((ext_vector_type(8))) __bf16 bf16x8;
typedef __attribute__((ext_vector_type(4))) float f32x4;

constexpr int Bc = 2, Sc = 2048, Dc = 1024, Hc = 16, HDc = 64;
constexpr int Kdim = 1024;
constexpr size_t SEG4M = 4194304;   // 4M elems
constexpr size_t SEG1M = 1048576;   // 1M elems

DEV_INLINE u16 f32_to_bf16(float f) {
    unsigned int u = __builtin_bit_cast(unsigned int, f);
    unsigned int r = (u + 0x7fffu + ((u >> 16) & 1u)) >> 16;
    return (u16)r;
}

// v_cvt_pk_bf16_f32: low16 = bf16(lo), high16 = bf16(hi)
DEV_INLINE uint32_t cvtpk_bf16(float lo, float hi) {
    uint32_t r;
    asm("v_cvt_pk_bf16_f32 %0, %1, %2" : "=v"(r) : "v"(lo), "v"(hi));
    return r;
}

DEV_INLINE f32x4 mfma16(bf16x8 a, bf16x8 b, f32x4 c) {
    return __builtin_amdgcn_mfma_f32_16x16x32_bf16(a, b, c, 0, 0, 0);
}

// async global->LDS, 16B per lane; lds dest must be wave-uniform base.
DEV_INLINE void gload_lds16(const u16* g, u16* lds) {
    __builtin_amdgcn_global_load_lds(
        (const __attribute__((address_space(1))) void*)g,
        (__attribute__((address_space(3))) void*)lds,
        16, 0, 0);
}

// ---------------- fp32 -> bf16, all 7 tensors in one launch ----------------
__global__ __launch_bounds__(256) void cvt_all_kernel(
        const float* __restrict__ q, const float* __restrict__ k,
        const float* __restrict__ v, const float* __restrict__ wq,
        const float* __restrict__ wk, const float* __restrict__ wv,
        const float* __restrict__ wo, u16* __restrict__ dst) {
    int b = blockIdx.x;
    const float* src; size_t doff; int lb;
    if (b < 2048)      { src = q;  lb = b;        doff = 0; }
    else if (b < 4096) { src = k;  lb = b - 2048; doff = SEG4M; }
    else if (b < 6144) { src = v;  lb = b - 4096; doff = 2 * SEG4M; }
    else if (b < 6656) { src = wq; lb = b - 6144; doff = 3 * SEG4M; }
    else if (b < 7168) { src = wk; lb = b - 6656; doff = 3 * SEG4M + SEG1M; }
    else if (b < 7680) { src = wv; lb = b - 7168; doff = 3 * SEG4M + 2 * SEG1M; }
    else               { src = wo; lb = b - 7680; doff = 3 * SEG4M + 3 * SEG1M; }
    size_t i = ((size_t)lb * 256 + threadIdx.x) * 8;
    float4 a = *reinterpret_cast<const float4*>(src + i);
    float4 c = *reinterpret_cast<const float4*>(src + i + 4);
    union { u16 u[8]; uint4 v4; } o;
    o.u[0] = f32_to_bf16(a.x); o.u[1] = f32_to_bf16(a.y);
    o.u[2] = f32_to_bf16(a.z); o.u[3] = f32_to_bf16(a.w);
    o.u[4] = f32_to_bf16(c.x); o.u[5] = f32_to_bf16(c.y);
    o.u[6] = f32_to_bf16(c.z); o.u[7] = f32_to_bf16(c.w);
    *reinterpret_cast<uint4*>(dst + doff + i) = o.v4;
}

// ---------------- fused QKV projection: 128x128 tiles, global_load_lds -----
// seg 0 -> Qh head-layout (scaled 1/8); seg 1 -> Kh head-layout;
// seg 2 -> Vt TRANSPOSED (BH,64,S) directly (transpose kernel folded in).
__global__ __launch_bounds__(256, 3) void gemm_qkv_kernel(
        const u16* __restrict__ Xb, const u16* __restrict__ Wb,
        u16* __restrict__ Ob) {
    __shared__ u16 Al[128 * 64];
    __shared__ u16 Bl[128 * 64];
    const int tid = threadIdx.x;
    const int l = tid & 63, w = tid >> 6;
    const int wm = w >> 1, wn = w & 1;
    const int l15 = l & 15, lg = l >> 4;
    const int lr = l >> 3, lc = (l & 7) * 8;

    int bid = blockIdx.x;                       // 768 blocks
    int wid = (bid & 7) * 96 + (bid >> 3);      // XCD-contiguous
    int mt = wid / 24, nt = wid % 24;
    int seg = nt >> 3, ntl = nt & 7;

    const u16* A = Xb + (size_t)seg * SEG4M + (size_t)mt * 128 * Kdim;
    const u16* W = Wb + (size_t)seg * SEG1M + (size_t)ntl * 128 * Kdim;

    f32x4 acc[4][4] = {};

    for (int kt = 0; kt < 16; ++kt) {
        const int kb = kt * 64;
#pragma unroll
        for (int i = 0; i < 4; ++i) {
            int j = w * 4 + i;
            gload_lds16(A + (size_t)(j * 8 + lr) * Kdim + kb + lc, &Al[j * 512]);
            gload_lds16(W + (size_t)(j * 8 + lr) * Kdim + kb + lc, &Bl[j * 512]);
        }
        asm volatile("s_waitcnt vmcnt(0)" ::: "memory");
        __syncthreads();
#pragma unroll
        for (int kk = 0; kk < 2; ++kk) {
            bf16x8 af[4], bfr[4];
#pragma unroll
            for (int mi = 0; mi < 4; ++mi)
                af[mi] = *reinterpret_cast<const bf16x8*>(&Al[(wm * 64 + mi * 16 + l15) * 64 + kk * 32 + lg * 8]);
#pragma unroll
            for (int ni = 0; ni < 4; ++ni)
                bfr[ni] = *reinterpret_cast<const bf16x8*>(&Bl[(wn * 64 + ni * 16 + l15) * 64 + kk * 32 + lg * 8]);
#pragma unroll
            for (int mi = 0; mi < 4; ++mi)
#pragma unroll
                for (int ni = 0; ni < 4; ++ni)
                    acc[mi][ni] = mfma16(af[mi], bfr[ni], acc[mi][ni]);
        }
        __syncthreads();
    }

    const int row0 = mt * 128 + wm * 64;
    const int col0 = ntl * 128 + wn * 64;

    if (seg == 2) {
        // V: write transposed Vt[(bh*64+d)*Sc + s], 4 s-consecutive packed
        u16* outT = Ob + 2 * SEG4M;
#pragma unroll
        for (int mi = 0; mi < 4; ++mi) {
            int m0 = row0 + mi * 16 + lg * 4;    // s base (4 consecutive)
            int b = m0 >> 11, s0 = m0 & 2047;
#pragma unroll
            for (int ni = 0; ni < 4; ++ni) {
                int n = col0 + ni * 16 + l15;
                int h = n >> 6, d = n & 63;
                int bh = b * Hc + h;
                uint2 pk;
                pk.x = ((uint32_t)f32_to_bf16(acc[mi][ni][1]) << 16) | f32_to_bf16(acc[mi][ni][0]);
                pk.y = ((uint32_t)f32_to_bf16(acc[mi][ni][3]) << 16) | f32_to_bf16(acc[mi][ni][2]);
                *reinterpret_cast<uint2*>(outT + ((size_t)bh * 64 + d) * Sc + s0) = pk;
            }
        }
    } else {
        const float scale = (seg == 0) ? 0.125f : 1.0f;
        u16* out = Ob + (size_t)seg * SEG4M;
#pragma unroll
        for (int mi = 0; mi < 4; ++mi)
#pragma unroll
            for (int r = 0; r < 4; ++r) {
                int m = row0 + mi * 16 + lg * 4 + r;
                int b = m >> 11, s = m & 2047;
#pragma unroll
                for (int ni = 0; ni < 4; ++ni) {
                    int n = col0 + ni * 16 + l15;
                    int h = n >> 6, d = n & 63;
                    out[(((size_t)b * Hc + h) * Sc + s) * HDc + d] =
                        f32_to_bf16(acc[mi][ni][r] * scale);
                }
            }
    }
}

// ---------------- output projection: 128x64 tiles -> fp32 ------------------
__global__ __launch_bounds__(256, 3) void gemm_out_kernel(
        const u16* __restrict__ A0, const u16* __restrict__ W0,
        float* __restrict__ outf) {
    __shared__ u16 Al[128 * 64];
    __shared__ u16 Bl[64 * 64];
    const int tid = threadIdx.x;
    const int l = tid & 63, w = tid >> 6;
    const int l15 = l & 15, lg = l >> 4;
    const int lr = l >> 3, lc = (l & 7) * 8;

    int bid = blockIdx.x;                      // 512 blocks
    int wid = (bid & 7) * 64 + (bid >> 3);
    int mt = wid >> 4, nt = wid & 15;

    const u16* A = A0 + (size_t)mt * 128 * Kdim;
    const u16* W = W0 + (size_t)nt * 64 * Kdim;

    f32x4 acc[2][4] = {};

    for (int kt = 0; kt < 16; ++kt) {
        const int kb = kt * 64;
#pragma unroll
        for (int i = 0; i < 4; ++i) {
            int j = w * 4 + i;
            gload_lds16(A + (size_t)(j * 8 + lr) * Kdim + kb + lc, &Al[j * 512]);
        }
#pragma unroll
        for (int i = 0; i < 2; ++i) {
            int j = w * 2 + i;
            gload_lds16(W + (size_t)(j * 8 + lr) * Kdim + kb + lc, &Bl[j * 512]);
        }
        asm volatile("s_waitcnt vmcnt(0)" ::: "memory");
        __syncthreads();
#pragma unroll
        for (int kk = 0; kk < 2; ++kk) {
            bf16x8 af[2], bfr[4];
#pragma unroll
            for (int mi = 0; mi < 2; ++mi)
                af[mi] = *reinterpret_cast<const bf16x8*>(&Al[(w * 32 + mi * 16 + l15) * 64 + kk * 32 + lg * 8]);
#pragma unroll
            for (int ni = 0; ni < 4; ++ni)
                bfr[ni] = *reinterpret_cast<const bf16x8*>(&Bl[(ni * 16 + l15) * 64 + kk * 32 + lg * 8]);
#pragma unroll
            for (int mi = 0; mi < 2; ++mi)
#pragma unroll
                for (int ni = 0; ni < 4; ++ni)
                    acc[mi][ni] = mfma16(af[mi], bfr[ni], acc[mi][ni]);
        }
        __syncthreads();
    }

#pragma unroll
    for (int mi = 0; mi < 2; ++mi)
#pragma unroll
        for (int r = 0; r < 4; ++r) {
            int m = mt * 128 + w * 32 + mi * 16 + lg * 4 + r;
#pragma unroll
            for (int ni = 0; ni < 4; ++ni) {
                int n = nt * 64 + ni * 16 + l15;
                outf[(size_t)m * 1024 + n] = acc[mi][ni][r];
            }
        }
}

// ---------------- causal flash attention, swapped-operand softmax ----------
// Qh,Kh: (BH,S,64) bf16 (Q pre-scaled); Vt: (BH,64,S) bf16.
// Grid 512 = 16 qt x 32 bh; block = 4 waves x 32 q-rows (QBLK=128), KVBLK=64.
// Swapped MFMAs: QK^T = mfma(K,Q) -> lane l15 = q-row holds 16 kpos values;
// softmax is lane-local + 2 shfl. PV = mfma(V,P) -> O^T, q stays lane-local.
__global__ __launch_bounds__(256, 2) void flash_attn_kernel(
        const u16* __restrict__ Qh, const u16* __restrict__ Kh,
        const u16* __restrict__ Vt, u16* __restrict__ Ctx) {
    __shared__ u16 Ksh[64][72];
    __shared__ u16 Vsh[64][72];
    __shared__ u16 Psh[4][2][16][72];

    const int tid = threadIdx.x;
    const int l = tid & 63, w = tid >> 6;
    const int l15 = l & 15, lg = l >> 4;

    const int bid = blockIdx.x;
    const int bh = bid & 31;                 // bh%8 pins to one XCD
    const int qt = 15 - (bid >> 5);          // big q-tiles dispatched first
    const int b = bh >> 4, h = bh & 15;
    const int qr0 = qt * 128 + w * 32;       // this wave's 32 q-rows

    // Q fragments (B-operand): lane holds Q[q=qr0+16mi+l15][32kk+8lg .. +7]
    const u16* qb = Qh + ((size_t)bh * Sc + qr0) * 64;
    bf16x8 aq[2][2];
#pragma unroll
    for (int mi = 0; mi < 2; ++mi)
#pragma unroll
        for (int kk = 0; kk < 2; ++kk)
            aq[mi][kk] = *reinterpret_cast<const bf16x8*>(
                qb + (size_t)(mi * 16 + l15) * 64 + kk * 32 + lg * 8);

    // O^T accumulator: o[mi][nd][r] = O[d=nd*16+4lg+r][q=l15+16mi]
    f32x4 o[2][4] = {};
    float m_run[2] = {-1e30f, -1e30f}, l_run[2] = {0.f, 0.f};

    const u16* kb0 = Kh + (size_t)bh * Sc * 64;
    const u16* vb0 = Vt + (size_t)bh * 64 * Sc;
    const int nkt = 2 * qt + 2;              // block trip count (max wave)
    const int kt_max_w = qr0 >> 6;           // this wave's last active tile

    uint4 rk[2], rv[2];
    auto load_kv = [&](int kt) {
#pragma unroll
        for (int i = 0; i < 2; ++i) {
            int f = i * 256 + tid, r = f >> 3, cc = (f & 7) * 8;
            rk[i] = *reinterpret_cast<const uint4*>(kb0 + ((size_t)kt * 64 + r) * 64 + cc);
            rv[i] = *reinterpret_cast<const uint4*>(vb0 + (size_t)r * Sc + kt * 64 + cc);
        }
    };
    auto store_kv = [&]() {
#pragma unroll
        for (int i = 0; i < 2; ++i) {
            int f = i * 256 + tid, r = f >> 3, cc = (f & 7) * 8;
            *reinterpret_cast<uint4*>(&Ksh[r][cc]) = rk[i];
            *reinterpret_cast<uint4*>(&Vsh[r][cc]) = rv[i];
        }
    };

    load_kv(0);
    for (int kt = 0; kt < nkt; ++kt) {
        store_kv();
        __syncthreads();
        if (kt + 1 < nkt) load_kv(kt + 1);   // prefetch overlaps compute

        if (kt <= kt_max_w) {
            // S^T = K Q^T: sc[mi][nk][r] = S[q=l15+16mi][kpos=16nk+4lg+r]
            f32x4 sc[2][4] = {};
#pragma unroll
            for (int kk = 0; kk < 2; ++kk) {
                bf16x8 kf[4];
#pragma unroll
                for (int nk = 0; nk < 4; ++nk)
                    kf[nk] = *reinterpret_cast<const bf16x8*>(&Ksh[nk * 16 + l15][kk * 32 + lg * 8]);
                __builtin_amdgcn_s_setprio(1);
#pragma unroll
                for (int mi = 0; mi < 2; ++mi)
#pragma unroll
                    for (int nk = 0; nk < 4; ++nk)
                        sc[mi][nk] = mfma16(kf[nk], aq[mi][kk], sc[mi][nk]);
                __builtin_amdgcn_s_setprio(0);
            }

            // causal mask only on this wave's diagonal tile
            if (kt == kt_max_w) {
                const int kb = kt * 64 + lg * 4;
#pragma unroll
                for (int mi = 0; mi < 2; ++mi) {
                    const int qg = qr0 + mi * 16 + l15;
#pragma unroll
                    for (int nk = 0; nk < 4; ++nk)
#pragma unroll
                        for (int r = 0; r < 4; ++r)
                            if (kb + nk * 16 + r > qg) sc[mi][nk][r] = -1e30f;
                }
            }

            // lane-local online softmax (q = l15 is lane-fixed)
#pragma unroll
            for (int mi = 0; mi < 2; ++mi) {
                float pmax = -1e30f;
#pragma unroll
                for (int nk = 0; nk < 4; ++nk)
#pragma unroll
                    for (int r = 0; r < 4; ++r) pmax = fmaxf(pmax, sc[mi][nk][r]);
                pmax = fmaxf(pmax, __shfl_xor(pmax, 16));
                pmax = fmaxf(pmax, __shfl_xor(pmax, 32));
                if (pmax > m_run[mi] + 8.f) {        // defer-max (T13)
                    float alpha = __expf(m_run[mi] - pmax);
                    l_run[mi] *= alpha;
#pragma unroll
                    for (int nd = 0; nd < 4; ++nd)
#pragma unroll
                        for (int r = 0; r < 4; ++r) o[mi][nd][r] *= alpha;
                    m_run[mi] = pmax;
                }
                float ssum = 0.f;
#pragma unroll
                for (int nk = 0; nk < 4; ++nk)
#pragma unroll
                    for (int r = 0; r < 4; ++r) {
                        float p = __expf(sc[mi][nk][r] - m_run[mi]);
                        sc[mi][nk][r] = p;
                        ssum += p;
                    }
                ssum += __shfl_xor(ssum, 16);
                ssum += __shfl_xor(ssum, 32);
                l_run[mi] += ssum;
                // pack P row (q=l15) -> Psh[w][mi][q][kpos], 4x ds_write_b64
#pragma unroll
                for (int nk = 0; nk < 4; ++nk) {
                    uint2 pk;
                    pk.x = cvtpk_bf16(sc[mi][nk][0], sc[mi][nk][1]);
                    pk.y = cvtpk_bf16(sc[mi][nk][2], sc[mi][nk][3]);
                    *reinterpret_cast<uint2*>(&Psh[w][mi][l15][nk * 16 + lg * 4]) = pk;
                }
            }
            asm volatile("s_waitcnt lgkmcnt(0)" ::: "memory");
            __builtin_amdgcn_sched_barrier(0);

            // O^T += V^T P^T : mfma(V, P) -> D[d][q]
#pragma unroll
            for (int kk = 0; kk < 2; ++kk) {
                bf16x8 vf[4], pa[2];
#pragma unroll
                for (int nd = 0; nd < 4; ++nd)
                    vf[nd] = *reinterpret_cast<const bf16x8*>(&Vsh[nd * 16 + l15][kk * 32 + lg * 8]);
#pragma unroll
                for (int mi = 0; mi < 2; ++mi)
                    pa[mi] = *reinterpret_cast<const bf16x8*>(&Psh[w][mi][l15][kk * 32 + lg * 8]);
                __builtin_amdgcn_s_setprio(1);
#pragma unroll
                for (int mi = 0; mi < 2; ++mi)
#pragma unroll
                    for (int nd = 0; nd < 4; ++nd)
                        o[mi][nd] = mfma16(vf[nd], pa[mi], o[mi][nd]);
                __builtin_amdgcn_s_setprio(0);
            }
        }
        __syncthreads();
    }

    // epilogue: normalize (per-lane q), write Ctx (B,S,D) bf16, 8B packed
#pragma unroll
    for (int mi = 0; mi < 2; ++mi) {
        float inv = 1.f / l_run[mi];
        int srow = qr0 + mi * 16 + l15;
        size_t base = ((size_t)b * Sc + srow) * Dc + h * 64;
#pragma unroll
        for (int nd = 0; nd < 4; ++nd) {
            uint2 pk;
            pk.x = cvtpk_bf16(o[mi][nd][0] * inv, o[mi][nd][1] * inv);
            pk.y = cvtpk_bf16(o[mi][nd][2] * inv, o[mi][nd][3] * inv);
            *reinterpret_cast<uint2*>(Ctx + base + nd * 16 + lg * 4) = pk;
        }
    }
}

// ---------------------------------------------------------------------------
extern "C" void kernel_launch(void* const* d_in, const int* in_sizes, int n_in,
                              void* d_out, int out_size, void* d_ws, size_t ws_size,
                              hipStream_t stream) {
    const float* q  = (const float*)d_in[0];
    const float* k  = (const float*)d_in[1];
    const float* v  = (const float*)d_in[2];
    const float* Wq = (const float*)d_in[4];
    const float* Wk = (const float*)d_in[5];
    const float* Wv = (const float*)d_in[6];
    const float* Wo = (const float*)d_in[7];

    u16* ws = (u16*)d_ws;
    u16* Xq  = ws;                       // 3 x 4M input bf16 (contiguous)
    u16* Wqb = ws + 3 * SEG4M;           // 4 x 1M weights bf16 (contiguous)
    u16* Wob = Wqb + 3 * SEG1M;
    u16* Qh  = ws + 4 * SEG4M;           // Q head-layout
    u16* Kh  = Qh + SEG4M;               // K head-layout
    u16* Vtr = Kh + SEG4M;               // V TRANSPOSED (written by gemm_qkv)
    u16* Ctx = ws;                       // alias Xq (dead after gemm_qkv)

    // 1) all conversions, one launch
    cvt_all_kernel<<<8192, 256, 0, stream>>>(q, k, v, Wq, Wk, Wv, Wo, ws);

    // 2) fused QKV projection (Q scaled 1/8; V written pre-transposed)
    gemm_qkv_kernel<<<768, 256, 0, stream>>>(Xq, Wqb, Qh);

    // 3) causal flash attention (swapped-operand softmax)
    flash_attn_kernel<<<512, 256, 0, stream>>>(Qh, Kh, Vtr, Ctx);

    // 4) output projection -> fp32
    gemm_out_kernel<<<512, 256, 0, stream>>>(Ctx, Wob, (float*)d_out);
}